// Round 4
// baseline (1165.778 us; speedup 1.0000x reference)
//
#include <hip/hip_runtime.h>
#include <cstdint>
#include <cstddef>

// Problem constants (from reference)
#define NN   50000
#define EE   800000
#define ETOT (EE + NN)      // + self loops
#define HC   256            // H*C
#define NEG_SLOPE 0.2f
#define SENT_WORDS 25000    // 100KB sentinel region (safe for bf16[50000] or f32[50000])
#define SENT_VAL 0x42C80000u  // 100.0f bit pattern

// ---- bf16 helpers (raw ushort, explicit RNE) ------------------------------
__device__ __forceinline__ float g4_bf2f(unsigned short h) {
    union { unsigned int u; float f; } v;
    v.u = ((unsigned int)h) << 16;
    return v.f;
}
__device__ __forceinline__ unsigned short g4_f2bf(float f) {
    union { float f; unsigned int u; } v;
    v.f = f;
    unsigned int u = v.u;
    u += 0x7fffu + ((u >> 16) & 1u);   // round-to-nearest-even
    return (unsigned short)(u >> 16);
}
// dual-dtype load: isf=1 -> float32 array, isf=0 -> bf16 array
__device__ __forceinline__ float g4_ld(const void* p, size_t i, int isf) {
    return isf ? ((const float*)p)[i] : g4_bf2f(((const unsigned short*)p)[i]);
}

// ---------------------------------------------------------------------------
// Dtype detection: flags[0]=1 iff float tensors are fp32 (else bf16),
// flags[1]=1 iff edge_index is int64 (else int32).
// ---------------------------------------------------------------------------
__global__ void g4_detect(const unsigned int* __restrict__ xw,
                          const int* __restrict__ ei32, int* __restrict__ flags) {
    __shared__ int cnt[256];
    int t = threadIdx.x;
    unsigned int w = xw[t];
    int e = (int)((w >> 23) & 0xffu);
    cnt[t] = (e >= 110 && e <= 135) ? 1 : 0;   // fp32 N(0,1) exponent band
    __syncthreads();
    for (int off = 128; off > 0; off >>= 1) {
        if (t < off) cnt[t] += cnt[t + off];
        __syncthreads();
    }
    if (t == 0) {
        flags[0] = (cnt[0] >= 128) ? 1 : 0;
        // int64 node ids < 2^31 -> high int32 words are all zero
        int i64 = (ei32[1] == 0 && ei32[3] == 0 && ei32[5] == 0 &&
                   ei32[7] == 0 && ei32[9] == 0) ? 1 : 0;
        flags[1] = i64;
    }
}

// ---------------------------------------------------------------------------
// Zero CSR counters + fill d_out sentinel (diagnostic; overwritten by head)
// ---------------------------------------------------------------------------
__global__ void g4_zero(int* __restrict__ deg, int* __restrict__ cnt,
                        unsigned int* __restrict__ outw) {
    int i = blockIdx.x * 256 + threadIdx.x;
    if (i < NN) { deg[i] = 0; cnt[i] = 0; }
    if (i < SENT_WORDS) outw[i] = SENT_VAL;
}

// ---------------------------------------------------------------------------
// CSR build (robust to int32/int64 edge_index via flags[1])
// ---------------------------------------------------------------------------
__global__ void g4_hist(const int* __restrict__ ei, const int* __restrict__ flags,
                        int* __restrict__ deg) {
    int e = blockIdx.x * blockDim.x + threadIdx.x;
    if (e >= ETOT) return;
    int i64 = flags[1];
    int d;
    if (e < EE) d = i64 ? ei[2 * (EE + e)] : ei[EE + e];
    else        d = e - EE;
    atomicAdd(&deg[d], 1);
}

__global__ void g4_scan_block(const int* __restrict__ deg, int* __restrict__ tmp,
                              int* __restrict__ partial) {
    __shared__ int sh[256];
    int i = blockIdx.x * 256 + threadIdx.x;
    int v = (i < NN) ? deg[i] : 0;
    sh[threadIdx.x] = v;
    __syncthreads();
    for (int off = 1; off < 256; off <<= 1) {
        int t = (threadIdx.x >= off) ? sh[threadIdx.x - off] : 0;
        __syncthreads();
        sh[threadIdx.x] += t;
        __syncthreads();
    }
    if (i < NN) tmp[i] = sh[threadIdx.x] - v;      // exclusive within block
    if (threadIdx.x == 255) partial[blockIdx.x] = sh[255];
}

__global__ void g4_scan_partial(int* __restrict__ partial, int nb,
                                int* __restrict__ rowptrN) {
    __shared__ int sh[256];
    int v = (threadIdx.x < nb) ? partial[threadIdx.x] : 0;
    sh[threadIdx.x] = v;
    __syncthreads();
    for (int off = 1; off < 256; off <<= 1) {
        int t = (threadIdx.x >= off) ? sh[threadIdx.x - off] : 0;
        __syncthreads();
        sh[threadIdx.x] += t;
        __syncthreads();
    }
    if (threadIdx.x < nb) partial[threadIdx.x] = sh[threadIdx.x] - v;
    if (threadIdx.x == 0) *rowptrN = ETOT;
}

__global__ void g4_scan_add(const int* __restrict__ tmp, const int* __restrict__ partial,
                            int* __restrict__ rowptr) {
    int i = blockIdx.x * 256 + threadIdx.x;
    if (i < NN) rowptr[i] = tmp[i] + partial[blockIdx.x];
}

__global__ void g4_fill_csr(const int* __restrict__ ei, const int* __restrict__ flags,
                            const int* __restrict__ rowptr,
                            int* __restrict__ cnt, int* __restrict__ col) {
    int e = blockIdx.x * blockDim.x + threadIdx.x;
    if (e >= ETOT) return;
    int i64 = flags[1];
    int s, d;
    if (e < EE) {
        s = i64 ? ei[2 * e] : ei[e];
        d = i64 ? ei[2 * (EE + e)] : ei[EE + e];
    } else {
        s = e - EE; d = e - EE;
    }
    int pos = rowptr[d] + atomicAdd(&cnt[d], 1);
    col[pos] = s;
}

// ---------------------------------------------------------------------------
// GEMM: C[M,Nc](bf16) = A[M,K] @ B[K,Nc], fp32 accum.
// a_mode: 0 -> A is external input (dtype per flags[0]); 1 -> A is internal bf16.
// B is external (dtype per flags[0]).
// ---------------------------------------------------------------------------
__global__ __launch_bounds__(256) void g4_gemm(
    const void* __restrict__ A, int a_mode, const void* __restrict__ B,
    const int* __restrict__ flags, unsigned short* __restrict__ C,
    int M, int K, int Nc) {
    __shared__ float As[64][17];
    __shared__ float Bs[16][64];
    const int isf = flags[0];
    const int af  = (a_mode == 0) ? isf : 0;   // internal buffers are always bf16
    const int tid = threadIdx.x;
    const int bm = blockIdx.x * 64;
    const int bn = blockIdx.y * 64;
    const int tx = tid & 15;
    const int ty = tid >> 4;
    float acc[4][4] = {};
    for (int k0 = 0; k0 < K; k0 += 16) {
        for (int i = tid; i < 64 * 16; i += 256) {
            int m = i >> 4, kk = i & 15;
            int gm = bm + m, gk = k0 + kk;
            float v = 0.f;
            if (gm < M && gk < K) v = g4_ld(A, (size_t)gm * K + gk, af);
            As[m][kk] = v;
        }
        for (int i = tid; i < 16 * 64; i += 256) {
            int kk = i >> 6, n = i & 63;
            int gk = k0 + kk, gn = bn + n;
            float v = 0.f;
            if (gk < K && gn < Nc) v = g4_ld(B, (size_t)gk * Nc + gn, isf);
            Bs[kk][n] = v;
        }
        __syncthreads();
        #pragma unroll
        for (int kk = 0; kk < 16; ++kk) {
            float a[4], b[4];
            #pragma unroll
            for (int i = 0; i < 4; i++) a[i] = As[ty * 4 + i][kk];
            #pragma unroll
            for (int j = 0; j < 4; j++) b[j] = Bs[kk][tx * 4 + j];
            #pragma unroll
            for (int i = 0; i < 4; i++)
                #pragma unroll
                for (int j = 0; j < 4; j++) acc[i][j] += a[i] * b[j];
        }
        __syncthreads();
    }
    for (int i = 0; i < 4; i++) {
        int gm = bm + ty * 4 + i;
        if (gm >= M) continue;
        for (int j = 0; j < 4; j++) {
            int gn = bn + tx * 4 + j;
            if (gn < Nc) C[(size_t)gm * Nc + gn] = g4_f2bf(acc[i][j]);
        }
    }
}

// ---------------------------------------------------------------------------
// Per-node attention logits. One wave per node; lane = channel.
// h: internal bf16. att_*: external (dtype per flags[0]).
// ---------------------------------------------------------------------------
__global__ __launch_bounds__(256) void g4_logits(
    const unsigned short* __restrict__ h, const void* __restrict__ att_src,
    const void* __restrict__ att_dst, const int* __restrict__ flags,
    float* __restrict__ a_src, float* __restrict__ a_dst) {
    int wid  = (blockIdx.x * blockDim.x + threadIdx.x) >> 6;
    int lane = threadIdx.x & 63;
    if (wid >= NN) return;
    const int isf = flags[0];
    const unsigned short* hp = h + (size_t)wid * HC;
    float s[4], d[4];
    #pragma unroll
    for (int hh = 0; hh < 4; hh++) {
        float v = g4_bf2f(hp[hh * 64 + lane]);
        s[hh] = v * g4_ld(att_src, hh * 64 + lane, isf);
        d[hh] = v * g4_ld(att_dst, hh * 64 + lane, isf);
    }
    for (int off = 32; off > 0; off >>= 1) {
        #pragma unroll
        for (int hh = 0; hh < 4; hh++) {
            s[hh] += __shfl_down(s[hh], off);
            d[hh] += __shfl_down(d[hh], off);
        }
    }
    if (lane == 0) {
        #pragma unroll
        for (int hh = 0; hh < 4; hh++) {
            a_src[wid * 4 + hh] = s[hh];
            a_dst[wid * 4 + hh] = d[hh];
        }
    }
}

// ---------------------------------------------------------------------------
// Wave-per-dst segment softmax + aggregation + bias + ELU -> bf16 out.
// ---------------------------------------------------------------------------
__global__ __launch_bounds__(256) void g4_aggregate(
    const unsigned short* __restrict__ h, const float* __restrict__ a_src,
    const float* __restrict__ a_dst, const int* __restrict__ rowptr,
    const int* __restrict__ col, const void* __restrict__ bias,
    const int* __restrict__ flags, unsigned short* __restrict__ xout) {
    int d    = (blockIdx.x * blockDim.x + threadIdx.x) >> 6;
    int lane = threadIdx.x & 63;
    if (d >= NN) return;
    const int isf = flags[0];
    const int start = rowptr[d], end = rowptr[d + 1];
    float ad[4];
    #pragma unroll
    for (int hh = 0; hh < 4; hh++) ad[hh] = a_dst[d * 4 + hh];

    // Pass A: max of leaky-relu logits
    float mx[4] = {-1e30f, -1e30f, -1e30f, -1e30f};
    for (int i = start + lane; i < end; i += 64) {
        int s = col[i];
        #pragma unroll
        for (int hh = 0; hh < 4; hh++) {
            float e = a_src[s * 4 + hh] + ad[hh];
            e = (e > 0.f) ? e : NEG_SLOPE * e;
            mx[hh] = fmaxf(mx[hh], e);
        }
    }
    for (int off = 32; off > 0; off >>= 1)
        #pragma unroll
        for (int hh = 0; hh < 4; hh++) mx[hh] = fmaxf(mx[hh], __shfl_xor(mx[hh], off));

    // Pass B: sum of exp
    float sm[4] = {0.f, 0.f, 0.f, 0.f};
    for (int i = start + lane; i < end; i += 64) {
        int s = col[i];
        #pragma unroll
        for (int hh = 0; hh < 4; hh++) {
            float e = a_src[s * 4 + hh] + ad[hh];
            e = (e > 0.f) ? e : NEG_SLOPE * e;
            sm[hh] += expf(e - mx[hh]);
        }
    }
    for (int off = 32; off > 0; off >>= 1)
        #pragma unroll
        for (int hh = 0; hh < 4; hh++) sm[hh] += __shfl_xor(sm[hh], off);
    float inv[4];
    #pragma unroll
    for (int hh = 0; hh < 4; hh++) inv[hh] = 1.f / sm[hh];

    // Pass C: weighted gather; lane = channel, alpha/src broadcast via shfl.
    float acc[4] = {0.f, 0.f, 0.f, 0.f};
    for (int base = start; base < end; base += 64) {
        int m = end - base;
        if (m > 64) m = 64;
        int   s_l   = 0;
        float al[4] = {0.f, 0.f, 0.f, 0.f};
        if (lane < m) {
            s_l = col[base + lane];
            #pragma unroll
            for (int hh = 0; hh < 4; hh++) {
                float e = a_src[s_l * 4 + hh] + ad[hh];
                e = (e > 0.f) ? e : NEG_SLOPE * e;
                al[hh] = expf(e - mx[hh]) * inv[hh];
            }
        }
        for (int j = 0; j < m; j++) {
            int s = __shfl(s_l, j);
            const unsigned short* hp = h + (size_t)s * HC;
            #pragma unroll
            for (int hh = 0; hh < 4; hh++)
                acc[hh] += __shfl(al[hh], j) * g4_bf2f(hp[hh * 64 + lane]);
        }
    }
    // Epilogue: +bias, ELU, bf16 store
    #pragma unroll
    for (int hh = 0; hh < 4; hh++) {
        float v = acc[hh] + g4_ld(bias, hh * 64 + lane, isf);
        v = (v > 0.f) ? v : (expf(v) - 1.f);
        xout[(size_t)d * HC + hh * 64 + lane] = g4_f2bf(v);
    }
}

// ---------------------------------------------------------------------------
// Fused MLP head. Output dtype follows flags[0]: fp32 if inputs fp32, else bf16.
// ---------------------------------------------------------------------------
__global__ __launch_bounds__(256) void g4_head(
    const unsigned short* __restrict__ x, const void* __restrict__ w1,
    const void* __restrict__ b1, const void* __restrict__ w2,
    const void* __restrict__ b2, const int* __restrict__ flags,
    void* __restrict__ outp) {
    int wid  = (blockIdx.x * blockDim.x + threadIdx.x) >> 6;
    int lane = threadIdx.x & 63;
    if (wid >= NN) return;
    const int isf = flags[0];
    const unsigned short* xp = x + (size_t)wid * HC;
    float acc = 0.f;
    for (int k = 0; k < HC; k += 64) {
        float xv = g4_bf2f(xp[k + lane]);
        #pragma unroll
        for (int j = 0; j < 64; j++) {
            float xb = __shfl(xv, j);
            acc += xb * g4_ld(w1, (size_t)(k + j) * 64 + lane, isf);
        }
    }
    float v = acc + g4_ld(b1, lane, isf);
    v = fmaxf(v, 0.f);
    float o = v * g4_ld(w2, lane, isf);
    for (int off = 32; off > 0; off >>= 1) o += __shfl_xor(o, off);
    if (lane == 0) {
        float r = o + g4_ld(b2, 0, isf);
        if (isf) ((float*)outp)[wid] = r;
        else     ((unsigned short*)outp)[wid] = g4_f2bf(r);
    }
}

// ---------------------------------------------------------------------------
extern "C" __attribute__((visibility("default")))
void kernel_launch(void* const* d_in, const int* in_sizes, int n_in,
                   void* d_out, int out_size, void* d_ws, size_t ws_size,
                   hipStream_t stream) {
    const void* x_in = d_in[0];
    const int*  ei   = (const int*)d_in[1];
    const void* W[3]    = {d_in[2], d_in[6], d_in[10]};
    const void* ASRC[3] = {d_in[3], d_in[7], d_in[11]};
    const void* ADST[3] = {d_in[4], d_in[8], d_in[12]};
    const void* BIAS[3] = {d_in[5], d_in[9], d_in[13]};
    const void* hw1 = d_in[14];
    const void* hb1 = d_in[15];
    const void* hw2 = d_in[16];
    const void* hb2 = d_in[17];

    // Workspace carve (~57 MB), no lambdas
    char* base = (char*)d_ws;
    size_t woff = 0;
#define G4_TAKE(name, type, count) \
    type* name = (type*)(base + woff); \
    woff += (((size_t)(count)) * sizeof(type) + 255) & ~(size_t)255;
    G4_TAKE(flags,   int, 8)
    G4_TAKE(deg,     int, NN)
    G4_TAKE(cnt,     int, NN)
    G4_TAKE(tmp,     int, NN)
    G4_TAKE(partial, int, 256)
    G4_TAKE(rowptr,  int, NN + 1)
    G4_TAKE(col,     int, ETOT)
    G4_TAKE(asr,     float, (size_t)NN * 4)
    G4_TAKE(adsb,    float, (size_t)NN * 4)
    G4_TAKE(hbuf,    unsigned short, (size_t)NN * HC)
    G4_TAKE(xbuf,    unsigned short, (size_t)NN * HC)
#undef G4_TAKE

    const int SCAN_BLOCKS = (NN + 255) / 256;          // 196
    const int EDGE_BLOCKS = (ETOT + 255) / 256;        // 3321
    const int WAVE_BLOCKS = (NN + 3) / 4;              // 12500 (4 waves/block)

    // Detect dtypes, zero counters, write d_out sentinel (diagnostic)
    g4_detect<<<1, 256, 0, stream>>>((const unsigned int*)x_in, ei, flags);
    g4_zero<<<SCAN_BLOCKS, 256, 0, stream>>>(deg, cnt, (unsigned int*)d_out);

    // CSR build
    g4_hist<<<EDGE_BLOCKS, 256, 0, stream>>>(ei, flags, deg);
    g4_scan_block<<<SCAN_BLOCKS, 256, 0, stream>>>(deg, tmp, partial);
    g4_scan_partial<<<1, 256, 0, stream>>>(partial, SCAN_BLOCKS, rowptr + NN);
    g4_scan_add<<<SCAN_BLOCKS, 256, 0, stream>>>(tmp, partial, rowptr);
    g4_fill_csr<<<EDGE_BLOCKS, 256, 0, stream>>>(ei, flags, rowptr, cnt, col);

    // 3 GAT layers
    dim3 ggrid((NN + 63) / 64, HC / 64);
    for (int l = 0; l < 3; l++) {
        if (l == 0) {
            g4_gemm<<<ggrid, 256, 0, stream>>>(x_in, 0, W[l], flags, hbuf, NN, 61, HC);
        } else {
            g4_gemm<<<ggrid, 256, 0, stream>>>(xbuf, 1, W[l], flags, hbuf, NN, HC, HC);
        }
        g4_logits<<<WAVE_BLOCKS, 256, 0, stream>>>(hbuf, ASRC[l], ADST[l], flags, asr, adsb);
        g4_aggregate<<<WAVE_BLOCKS, 256, 0, stream>>>(hbuf, asr, adsb, rowptr, col,
                                                      BIAS[l], flags, xbuf);
    }
    // Head
    g4_head<<<WAVE_BLOCKS, 256, 0, stream>>>(xbuf, hw1, hb1, hw2, hb2, flags, d_out);
}

// Round 5
// 909.958 us; speedup vs baseline: 1.2811x; 1.2811x over previous
//
#include <hip/hip_runtime.h>
#include <cstdint>
#include <cstddef>

// Problem constants (from reference)
#define NN   50000
#define EE   800000
#define ETOT (EE + NN)      // + self loops
#define HC   256            // H*C
#define NEG_SLOPE 0.2f
#define SENT_WORDS 25000
#define SENT_VAL 0x42C80000u

// ---- bf16 helpers (raw ushort, explicit RNE) ------------------------------
__device__ __forceinline__ float g4_bf2f(unsigned short h) {
    union { unsigned int u; float f; } v;
    v.u = ((unsigned int)h) << 16;
    return v.f;
}
__device__ __forceinline__ unsigned short g4_f2bf(float f) {
    union { float f; unsigned int u; } v;
    v.f = f;
    unsigned int u = v.u;
    u += 0x7fffu + ((u >> 16) & 1u);   // round-to-nearest-even
    return (unsigned short)(u >> 16);
}
// dual-dtype load: isf=1 -> float32 array, isf=0 -> bf16 array
__device__ __forceinline__ float g4_ld(const void* p, size_t i, int isf) {
    return isf ? ((const float*)p)[i] : g4_bf2f(((const unsigned short*)p)[i]);
}

// ---------------------------------------------------------------------------
// Dtype detection: flags[0]=1 iff float tensors are fp32 (else bf16),
// flags[1]=1 iff edge_index is int64 (else int32).
// ---------------------------------------------------------------------------
__global__ void g4_detect(const unsigned int* __restrict__ xw,
                          const int* __restrict__ ei32, int* __restrict__ flags) {
    __shared__ int cnt[256];
    int t = threadIdx.x;
    unsigned int w = xw[t];
    int e = (int)((w >> 23) & 0xffu);
    cnt[t] = (e >= 110 && e <= 135) ? 1 : 0;   // fp32 N(0,1) exponent band
    __syncthreads();
    for (int off = 128; off > 0; off >>= 1) {
        if (t < off) cnt[t] += cnt[t + off];
        __syncthreads();
    }
    if (t == 0) {
        flags[0] = (cnt[0] >= 128) ? 1 : 0;
        int i64 = (ei32[1] == 0 && ei32[3] == 0 && ei32[5] == 0 &&
                   ei32[7] == 0 && ei32[9] == 0) ? 1 : 0;
        flags[1] = i64;
    }
}

// ---------------------------------------------------------------------------
// Zero CSR counters + fill d_out sentinel (diagnostic; overwritten by head)
// ---------------------------------------------------------------------------
__global__ void g4_zero(int* __restrict__ deg, int* __restrict__ cnt,
                        unsigned int* __restrict__ outw) {
    int i = blockIdx.x * 256 + threadIdx.x;
    if (i < NN) { deg[i] = 0; cnt[i] = 0; }
    if (i < SENT_WORDS) outw[i] = SENT_VAL;
}

// ---------------------------------------------------------------------------
// CSR build (robust to int32/int64 edge_index via flags[1])
// ---------------------------------------------------------------------------
__global__ void g4_hist(const int* __restrict__ ei, const int* __restrict__ flags,
                        int* __restrict__ deg) {
    int e = blockIdx.x * blockDim.x + threadIdx.x;
    if (e >= ETOT) return;
    int i64 = flags[1];
    int d;
    if (e < EE) d = i64 ? ei[2 * (EE + e)] : ei[EE + e];
    else        d = e - EE;
    atomicAdd(&deg[d], 1);
}

__global__ void g4_scan_block(const int* __restrict__ deg, int* __restrict__ tmp,
                              int* __restrict__ partial) {
    __shared__ int sh[256];
    int i = blockIdx.x * 256 + threadIdx.x;
    int v = (i < NN) ? deg[i] : 0;
    sh[threadIdx.x] = v;
    __syncthreads();
    for (int off = 1; off < 256; off <<= 1) {
        int t = (threadIdx.x >= off) ? sh[threadIdx.x - off] : 0;
        __syncthreads();
        sh[threadIdx.x] += t;
        __syncthreads();
    }
    if (i < NN) tmp[i] = sh[threadIdx.x] - v;      // exclusive within block
    if (threadIdx.x == 255) partial[blockIdx.x] = sh[255];
}

__global__ void g4_scan_partial(int* __restrict__ partial, int nb,
                                int* __restrict__ rowptrN) {
    __shared__ int sh[256];
    int v = (threadIdx.x < nb) ? partial[threadIdx.x] : 0;
    sh[threadIdx.x] = v;
    __syncthreads();
    for (int off = 1; off < 256; off <<= 1) {
        int t = (threadIdx.x >= off) ? sh[threadIdx.x - off] : 0;
        __syncthreads();
        sh[threadIdx.x] += t;
        __syncthreads();
    }
    if (threadIdx.x < nb) partial[threadIdx.x] = sh[threadIdx.x] - v;
    if (threadIdx.x == 0) *rowptrN = ETOT;
}

__global__ void g4_scan_add(const int* __restrict__ tmp, const int* __restrict__ partial,
                            int* __restrict__ rowptr) {
    int i = blockIdx.x * 256 + threadIdx.x;
    if (i < NN) rowptr[i] = tmp[i] + partial[blockIdx.x];
}

__global__ void g4_fill_csr(const int* __restrict__ ei, const int* __restrict__ flags,
                            const int* __restrict__ rowptr,
                            int* __restrict__ cnt, int* __restrict__ col) {
    int e = blockIdx.x * blockDim.x + threadIdx.x;
    if (e >= ETOT) return;
    int i64 = flags[1];
    int s, d;
    if (e < EE) {
        s = i64 ? ei[2 * e] : ei[e];
        d = i64 ? ei[2 * (EE + e)] : ei[EE + e];
    } else {
        s = e - EE; d = e - EE;
    }
    int pos = rowptr[d] + atomicAdd(&cnt[d], 1);
    col[pos] = s;
}

// ---------------------------------------------------------------------------
// GEMM: C[M,Nc](bf16) = A[M,K] @ B[K,Nc], fp32 accum.
// a_mode: 0 -> A is external input (dtype per flags[0]); 1 -> A is internal bf16.
// ---------------------------------------------------------------------------
__global__ __launch_bounds__(256) void g4_gemm(
    const void* __restrict__ A, int a_mode, const void* __restrict__ B,
    const int* __restrict__ flags, unsigned short* __restrict__ C,
    int M, int K, int Nc) {
    __shared__ float As[64][17];
    __shared__ float Bs[16][64];
    const int isf = flags[0];
    const int af  = (a_mode == 0) ? isf : 0;   // internal buffers are always bf16
    const int tid = threadIdx.x;
    const int bm = blockIdx.x * 64;
    const int bn = blockIdx.y * 64;
    const int tx = tid & 15;
    const int ty = tid >> 4;
    float acc[4][4] = {};
    for (int k0 = 0; k0 < K; k0 += 16) {
        for (int i = tid; i < 64 * 16; i += 256) {
            int m = i >> 4, kk = i & 15;
            int gm = bm + m, gk = k0 + kk;
            float v = 0.f;
            if (gm < M && gk < K) v = g4_ld(A, (size_t)gm * K + gk, af);
            As[m][kk] = v;
        }
        for (int i = tid; i < 16 * 64; i += 256) {
            int kk = i >> 6, n = i & 63;
            int gk = k0 + kk, gn = bn + n;
            float v = 0.f;
            if (gk < K && gn < Nc) v = g4_ld(B, (size_t)gk * Nc + gn, isf);
            Bs[kk][n] = v;
        }
        __syncthreads();
        #pragma unroll
        for (int kk = 0; kk < 16; ++kk) {
            float a[4], b[4];
            #pragma unroll
            for (int i = 0; i < 4; i++) a[i] = As[ty * 4 + i][kk];
            #pragma unroll
            for (int j = 0; j < 4; j++) b[j] = Bs[kk][tx * 4 + j];
            #pragma unroll
            for (int i = 0; i < 4; i++)
                #pragma unroll
                for (int j = 0; j < 4; j++) acc[i][j] += a[i] * b[j];
        }
        __syncthreads();
    }
    for (int i = 0; i < 4; i++) {
        int gm = bm + ty * 4 + i;
        if (gm >= M) continue;
        for (int j = 0; j < 4; j++) {
            int gn = bn + tx * 4 + j;
            if (gn < Nc) C[(size_t)gm * Nc + gn] = g4_f2bf(acc[i][j]);
        }
    }
}

// ---------------------------------------------------------------------------
// Per-node attention logits. One wave per node; lane = channel.
// ---------------------------------------------------------------------------
__global__ __launch_bounds__(256) void g4_logits(
    const unsigned short* __restrict__ h, const void* __restrict__ att_src,
    const void* __restrict__ att_dst, const int* __restrict__ flags,
    float* __restrict__ a_src, float* __restrict__ a_dst) {
    int wid  = (blockIdx.x * blockDim.x + threadIdx.x) >> 6;
    int lane = threadIdx.x & 63;
    if (wid >= NN) return;
    const int isf = flags[0];
    const unsigned short* hp = h + (size_t)wid * HC;
    float s[4], d[4];
    #pragma unroll
    for (int hh = 0; hh < 4; hh++) {
        float v = g4_bf2f(hp[hh * 64 + lane]);
        s[hh] = v * g4_ld(att_src, hh * 64 + lane, isf);
        d[hh] = v * g4_ld(att_dst, hh * 64 + lane, isf);
    }
    for (int off = 32; off > 0; off >>= 1) {
        #pragma unroll
        for (int hh = 0; hh < 4; hh++) {
            s[hh] += __shfl_down(s[hh], off);
            d[hh] += __shfl_down(d[hh], off);
        }
    }
    if (lane == 0) {
        #pragma unroll
        for (int hh = 0; hh < 4; hh++) {
            a_src[wid * 4 + hh] = s[hh];
            a_dst[wid * 4 + hh] = d[hh];
        }
    }
}

// ---------------------------------------------------------------------------
// Wave-per-dst segment softmax + aggregation + bias + ELU -> bf16 out.
// ---------------------------------------------------------------------------
__global__ __launch_bounds__(256) void g4_aggregate(
    const unsigned short* __restrict__ h, const float* __restrict__ a_src,
    const float* __restrict__ a_dst, const int* __restrict__ rowptr,
    const int* __restrict__ col, const void* __restrict__ bias,
    const int* __restrict__ flags, unsigned short* __restrict__ xout) {
    int d    = (blockIdx.x * blockDim.x + threadIdx.x) >> 6;
    int lane = threadIdx.x & 63;
    if (d >= NN) return;
    const int isf = flags[0];
    const int start = rowptr[d], end = rowptr[d + 1];
    float ad[4];
    #pragma unroll
    for (int hh = 0; hh < 4; hh++) ad[hh] = a_dst[d * 4 + hh];

    // Pass A: max of leaky-relu logits
    float mx[4] = {-1e30f, -1e30f, -1e30f, -1e30f};
    for (int i = start + lane; i < end; i += 64) {
        int s = col[i];
        #pragma unroll
        for (int hh = 0; hh < 4; hh++) {
            float e = a_src[s * 4 + hh] + ad[hh];
            e = (e > 0.f) ? e : NEG_SLOPE * e;
            mx[hh] = fmaxf(mx[hh], e);
        }
    }
    for (int off = 32; off > 0; off >>= 1)
        #pragma unroll
        for (int hh = 0; hh < 4; hh++) mx[hh] = fmaxf(mx[hh], __shfl_xor(mx[hh], off));

    // Pass B: sum of exp
    float sm[4] = {0.f, 0.f, 0.f, 0.f};
    for (int i = start + lane; i < end; i += 64) {
        int s = col[i];
        #pragma unroll
        for (int hh = 0; hh < 4; hh++) {
            float e = a_src[s * 4 + hh] + ad[hh];
            e = (e > 0.f) ? e : NEG_SLOPE * e;
            sm[hh] += expf(e - mx[hh]);
        }
    }
    for (int off = 32; off > 0; off >>= 1)
        #pragma unroll
        for (int hh = 0; hh < 4; hh++) sm[hh] += __shfl_xor(sm[hh], off);
    float inv[4];
    #pragma unroll
    for (int hh = 0; hh < 4; hh++) inv[hh] = 1.f / sm[hh];

    // Pass C: weighted gather; lane = channel, alpha/src broadcast via shfl.
    float acc[4] = {0.f, 0.f, 0.f, 0.f};
    for (int base = start; base < end; base += 64) {
        int m = end - base;
        if (m > 64) m = 64;
        int   s_l   = 0;
        float al[4] = {0.f, 0.f, 0.f, 0.f};
        if (lane < m) {
            s_l = col[base + lane];
            #pragma unroll
            for (int hh = 0; hh < 4; hh++) {
                float e = a_src[s_l * 4 + hh] + ad[hh];
                e = (e > 0.f) ? e : NEG_SLOPE * e;
                al[hh] = expf(e - mx[hh]) * inv[hh];
            }
        }
        for (int j = 0; j < m; j++) {
            int s = __shfl(s_l, j);
            const unsigned short* hp = h + (size_t)s * HC;
            #pragma unroll
            for (int hh = 0; hh < 4; hh++)
                acc[hh] += __shfl(al[hh], j) * g4_bf2f(hp[hh * 64 + lane]);
        }
    }
    // Epilogue: +bias, ELU, bf16 store
    #pragma unroll
    for (int hh = 0; hh < 4; hh++) {
        float v = acc[hh] + g4_ld(bias, hh * 64 + lane, isf);
        v = (v > 0.f) ? v : (expf(v) - 1.f);
        xout[(size_t)d * HC + hh * 64 + lane] = g4_f2bf(v);
    }
}

// ---------------------------------------------------------------------------
// Fused MLP head, GEMM-tiled: 64 nodes/block, K=256 through LDS, 4x4 micro-
// tile over the 64 hidden cols, fused relu + b1 + dot(w2) + b2 epilogue.
// out[n] = relu(x[n]@W1+b1)@w2 + b2
// ---------------------------------------------------------------------------
__global__ __launch_bounds__(256) void g4_head2(
    const unsigned short* __restrict__ x, const void* __restrict__ w1,
    const void* __restrict__ b1, const void* __restrict__ w2,
    const void* __restrict__ b2, const int* __restrict__ flags,
    void* __restrict__ outp) {
    __shared__ float As[64][17];    // x tile: 64 nodes x 16 k
    __shared__ float Bs[16][64];    // w1 slice: 16 k x 64 hidden
    __shared__ float red[64][17];   // row-reduction: 64 nodes x 16 col-groups
    const int isf = flags[0];
    const int tid = threadIdx.x;
    const int bm  = blockIdx.x * 64;
    const int tx  = tid & 15;       // col group (4 hidden cols)
    const int ty  = tid >> 4;       // row group (4 nodes)
    float acc[4][4] = {};
    for (int k0 = 0; k0 < HC; k0 += 16) {
        for (int i = tid; i < 64 * 16; i += 256) {
            int m = i >> 4, kk = i & 15;
            int gm = bm + m;
            float v = 0.f;
            if (gm < NN) v = g4_bf2f(x[(size_t)gm * HC + k0 + kk]);
            As[m][kk] = v;
        }
        for (int i = tid; i < 16 * 64; i += 256) {
            int kk = i >> 6, n = i & 63;
            Bs[kk][n] = g4_ld(w1, (size_t)(k0 + kk) * 64 + n, isf);
        }
        __syncthreads();
        #pragma unroll
        for (int kk = 0; kk < 16; ++kk) {
            float a[4], b[4];
            #pragma unroll
            for (int i = 0; i < 4; i++) a[i] = As[ty * 4 + i][kk];
            #pragma unroll
            for (int j = 0; j < 4; j++) b[j] = Bs[kk][tx * 4 + j];
            #pragma unroll
            for (int i = 0; i < 4; i++)
                #pragma unroll
                for (int j = 0; j < 4; j++) acc[i][j] += a[i] * b[j];
        }
        __syncthreads();
    }
    // Epilogue: +b1, relu, *w2, partial row sums -> LDS
    float b1v[4], w2v[4];
    #pragma unroll
    for (int j = 0; j < 4; j++) {
        b1v[j] = g4_ld(b1, tx * 4 + j, isf);
        w2v[j] = g4_ld(w2, tx * 4 + j, isf);
    }
    #pragma unroll
    for (int i = 0; i < 4; i++) {
        float s = 0.f;
        #pragma unroll
        for (int j = 0; j < 4; j++) {
            float v = acc[i][j] + b1v[j];
            v = fmaxf(v, 0.f);
            s += v * w2v[j];
        }
        red[ty * 4 + i][tx] = s;
    }
    __syncthreads();
    if (tid < 64) {
        float s = 0.f;
        #pragma unroll
        for (int g = 0; g < 16; g++) s += red[tid][g];
        int gm = bm + tid;
        if (gm < NN) {
            float r = s + g4_ld(b2, 0, isf);
            if (isf) ((float*)outp)[gm] = r;
            else     ((unsigned short*)outp)[gm] = g4_f2bf(r);
        }
    }
}

// ---------------------------------------------------------------------------
extern "C" __attribute__((visibility("default")))
void kernel_launch(void* const* d_in, const int* in_sizes, int n_in,
                   void* d_out, int out_size, void* d_ws, size_t ws_size,
                   hipStream_t stream) {
    const void* x_in = d_in[0];
    const int*  ei   = (const int*)d_in[1];
    const void* W[3]    = {d_in[2], d_in[6], d_in[10]};
    const void* ASRC[3] = {d_in[3], d_in[7], d_in[11]};
    const void* ADST[3] = {d_in[4], d_in[8], d_in[12]};
    const void* BIAS[3] = {d_in[5], d_in[9], d_in[13]};
    const void* hw1 = d_in[14];
    const void* hb1 = d_in[15];
    const void* hw2 = d_in[16];
    const void* hb2 = d_in[17];

    // Workspace carve (~57 MB), no lambdas
    char* base = (char*)d_ws;
    size_t woff = 0;
#define G4_TAKE(name, type, count) \
    type* name = (type*)(base + woff); \
    woff += (((size_t)(count)) * sizeof(type) + 255) & ~(size_t)255;
    G4_TAKE(flags,   int, 8)
    G4_TAKE(deg,     int, NN)
    G4_TAKE(cnt,     int, NN)
    G4_TAKE(tmp,     int, NN)
    G4_TAKE(partial, int, 256)
    G4_TAKE(rowptr,  int, NN + 1)
    G4_TAKE(col,     int, ETOT)
    G4_TAKE(asr,     float, (size_t)NN * 4)
    G4_TAKE(adsb,    float, (size_t)NN * 4)
    G4_TAKE(hbuf,    unsigned short, (size_t)NN * HC)
    G4_TAKE(xbuf,    unsigned short, (size_t)NN * HC)
#undef G4_TAKE

    const int SCAN_BLOCKS = (NN + 255) / 256;          // 196
    const int EDGE_BLOCKS = (ETOT + 255) / 256;        // 3321
    const int WAVE_BLOCKS = (NN + 3) / 4;              // 12500 (4 waves/block)
    const int TILE_BLOCKS = (NN + 63) / 64;            // 782

    // Detect dtypes, zero counters, write d_out sentinel (diagnostic)
    g4_detect<<<1, 256, 0, stream>>>((const unsigned int*)x_in, ei, flags);
    g4_zero<<<SCAN_BLOCKS, 256, 0, stream>>>(deg, cnt, (unsigned int*)d_out);

    // CSR build
    g4_hist<<<EDGE_BLOCKS, 256, 0, stream>>>(ei, flags, deg);
    g4_scan_block<<<SCAN_BLOCKS, 256, 0, stream>>>(deg, tmp, partial);
    g4_scan_partial<<<1, 256, 0, stream>>>(partial, SCAN_BLOCKS, rowptr + NN);
    g4_scan_add<<<SCAN_BLOCKS, 256, 0, stream>>>(tmp, partial, rowptr);
    g4_fill_csr<<<EDGE_BLOCKS, 256, 0, stream>>>(ei, flags, rowptr, cnt, col);

    // 3 GAT layers
    dim3 ggrid((NN + 63) / 64, HC / 64);
    for (int l = 0; l < 3; l++) {
        if (l == 0) {
            g4_gemm<<<ggrid, 256, 0, stream>>>(x_in, 0, W[l], flags, hbuf, NN, 61, HC);
        } else {
            g4_gemm<<<ggrid, 256, 0, stream>>>(xbuf, 1, W[l], flags, hbuf, NN, HC, HC);
        }
        g4_logits<<<WAVE_BLOCKS, 256, 0, stream>>>(hbuf, ASRC[l], ADST[l], flags, asr, adsb);
        g4_aggregate<<<WAVE_BLOCKS, 256, 0, stream>>>(hbuf, asr, adsb, rowptr, col,
                                                      BIAS[l], flags, xbuf);
    }
    // Head (fused GEMM-tiled)
    g4_head2<<<TILE_BLOCKS, 256, 0, stream>>>(xbuf, hw1, hb1, hw2, hb2, flags, d_out);
}

// Round 6
// 712.374 us; speedup vs baseline: 1.6365x; 1.2774x over previous
//
#include <hip/hip_runtime.h>
#include <cstdint>
#include <cstddef>

// Problem constants (from reference)
#define NN   50000
#define EE   800000
#define ETOT (EE + NN)      // + self loops
#define HC   256            // H*C
#define NEG_SLOPE 0.2f
#define SENT_WORDS 25000
#define SENT_VAL 0x42C80000u

typedef __attribute__((ext_vector_type(8))) short g4_bf16x8;
typedef __attribute__((ext_vector_type(4))) float g4_f32x4;

// ---- bf16 helpers (raw ushort, explicit RNE) ------------------------------
__device__ __forceinline__ float g4_bf2f(unsigned short h) {
    union { unsigned int u; float f; } v;
    v.u = ((unsigned int)h) << 16;
    return v.f;
}
__device__ __forceinline__ unsigned short g4_f2bf(float f) {
    union { float f; unsigned int u; } v;
    v.f = f;
    unsigned int u = v.u;
    u += 0x7fffu + ((u >> 16) & 1u);   // round-to-nearest-even
    return (unsigned short)(u >> 16);
}
// dual-dtype load: isf=1 -> float32 array, isf=0 -> bf16 array
__device__ __forceinline__ float g4_ld(const void* p, size_t i, int isf) {
    return isf ? ((const float*)p)[i] : g4_bf2f(((const unsigned short*)p)[i]);
}

// ---------------------------------------------------------------------------
// Dtype detection: flags[0]=1 iff float tensors are fp32 (else bf16),
// flags[1]=1 iff edge_index is int64 (else int32).
// ---------------------------------------------------------------------------
__global__ void g4_detect(const unsigned int* __restrict__ xw,
                          const int* __restrict__ ei32, int* __restrict__ flags) {
    __shared__ int cnt[256];
    int t = threadIdx.x;
    unsigned int w = xw[t];
    int e = (int)((w >> 23) & 0xffu);
    cnt[t] = (e >= 110 && e <= 135) ? 1 : 0;   // fp32 N(0,1) exponent band
    __syncthreads();
    for (int off = 128; off > 0; off >>= 1) {
        if (t < off) cnt[t] += cnt[t + off];
        __syncthreads();
    }
    if (t == 0) {
        flags[0] = (cnt[0] >= 128) ? 1 : 0;
        int i64 = (ei32[1] == 0 && ei32[3] == 0 && ei32[5] == 0 &&
                   ei32[7] == 0 && ei32[9] == 0) ? 1 : 0;
        flags[1] = i64;
    }
}

// ---------------------------------------------------------------------------
// Zero CSR counters + fill d_out sentinel (diagnostic; overwritten by head)
// ---------------------------------------------------------------------------
__global__ void g4_zero(int* __restrict__ deg, int* __restrict__ cnt,
                        unsigned int* __restrict__ outw) {
    int i = blockIdx.x * 256 + threadIdx.x;
    if (i < NN) { deg[i] = 0; cnt[i] = 0; }
    if (i < SENT_WORDS) outw[i] = SENT_VAL;
}

// ---------------------------------------------------------------------------
// CSR build (robust to int32/int64 edge_index via flags[1])
// ---------------------------------------------------------------------------
__global__ void g4_hist(const int* __restrict__ ei, const int* __restrict__ flags,
                        int* __restrict__ deg) {
    int e = blockIdx.x * blockDim.x + threadIdx.x;
    if (e >= ETOT) return;
    int i64 = flags[1];
    int d;
    if (e < EE) d = i64 ? ei[2 * (EE + e)] : ei[EE + e];
    else        d = e - EE;
    atomicAdd(&deg[d], 1);
}

__global__ void g4_scan_block(const int* __restrict__ deg, int* __restrict__ tmp,
                              int* __restrict__ partial) {
    __shared__ int sh[256];
    int i = blockIdx.x * 256 + threadIdx.x;
    int v = (i < NN) ? deg[i] : 0;
    sh[threadIdx.x] = v;
    __syncthreads();
    for (int off = 1; off < 256; off <<= 1) {
        int t = (threadIdx.x >= off) ? sh[threadIdx.x - off] : 0;
        __syncthreads();
        sh[threadIdx.x] += t;
        __syncthreads();
    }
    if (i < NN) tmp[i] = sh[threadIdx.x] - v;      // exclusive within block
    if (threadIdx.x == 255) partial[blockIdx.x] = sh[255];
}

__global__ void g4_scan_partial(int* __restrict__ partial, int nb,
                                int* __restrict__ rowptrN) {
    __shared__ int sh[256];
    int v = (threadIdx.x < nb) ? partial[threadIdx.x] : 0;
    sh[threadIdx.x] = v;
    __syncthreads();
    for (int off = 1; off < 256; off <<= 1) {
        int t = (threadIdx.x >= off) ? sh[threadIdx.x - off] : 0;
        __syncthreads();
        sh[threadIdx.x] += t;
        __syncthreads();
    }
    if (threadIdx.x < nb) partial[threadIdx.x] = sh[threadIdx.x] - v;
    if (threadIdx.x == 0) *rowptrN = ETOT;
}

__global__ void g4_scan_add(const int* __restrict__ tmp, const int* __restrict__ partial,
                            int* __restrict__ rowptr) {
    int i = blockIdx.x * 256 + threadIdx.x;
    if (i < NN) rowptr[i] = tmp[i] + partial[blockIdx.x];
}

__global__ void g4_fill_csr(const int* __restrict__ ei, const int* __restrict__ flags,
                            const int* __restrict__ rowptr,
                            int* __restrict__ cnt, int* __restrict__ col) {
    int e = blockIdx.x * blockDim.x + threadIdx.x;
    if (e >= ETOT) return;
    int i64 = flags[1];
    int s, d;
    if (e < EE) {
        s = i64 ? ei[2 * e] : ei[e];
        d = i64 ? ei[2 * (EE + e)] : ei[EE + e];
    } else {
        s = e - EE; d = e - EE;
    }
    int pos = rowptr[d] + atomicAdd(&cnt[d], 1);
    col[pos] = s;
}

// ---------------------------------------------------------------------------
// MFMA GEMM: C[M,Nc](bf16) = A[M,K] @ B[K,Nc], fp32 accum via matrix cores.
// 128x128 block tile, 4 waves in 2x2, each wave 4x4 grid of 16x16x32 MFMA.
// a_mode: 0 -> A external (dtype per flags[0]); 1 -> A internal bf16.
// Generic K (zero-padded to multiple of 32 in LDS).
// ---------------------------------------------------------------------------
#define LDK 40   // padded k-stride in shorts (80 B: 16B-aligned, even bank spread)
__global__ __launch_bounds__(256) void g4_gemm_mfma(
    const void* __restrict__ A, int a_mode, const void* __restrict__ B,
    const int* __restrict__ flags, unsigned short* __restrict__ C,
    int M, int K, int Nc) {
    __shared__ short As[128 * LDK];
    __shared__ short Bs[128 * LDK];
    const int isf = flags[0];
    const int af  = (a_mode == 0) ? isf : 0;
    const int tid  = threadIdx.x;
    const int lane = tid & 63;
    const int wave = tid >> 6;
    const int wr = wave >> 1;      // wave row (0..1) -> 64 rows
    const int wc = wave & 1;       // wave col (0..1) -> 64 cols
    const int quad = lane >> 4;    // 0..3
    const int l15  = lane & 15;
    const int bm = blockIdx.x * 128;
    const int bn = blockIdx.y * 128;
    // A fast path: bf16, K multiple of 16 (=> 16B-aligned rows)
    const int a_vec = (af == 0) && ((K & 15) == 0);

    g4_f32x4 acc[4][4];
    #pragma unroll
    for (int it = 0; it < 4; it++)
        #pragma unroll
        for (int jt = 0; jt < 4; jt++) {
            acc[it][jt].x = 0.f; acc[it][jt].y = 0.f;
            acc[it][jt].z = 0.f; acc[it][jt].w = 0.f;
        }

    for (int k0 = 0; k0 < K; k0 += 32) {
        // ---- stage A tile: 128 rows x 32 k. thread: row=tid>>1, kc=(tid&1)*16
        {
            int row = tid >> 1;
            int kc  = (tid & 1) * 16;
            int gm  = bm + row;
            short v[16];
            if (a_vec && gm < M && (k0 + kc + 16) <= K) {
                const short* ap = (const short*)A + (size_t)gm * K + k0 + kc;
                *(g4_bf16x8*)&v[0] = *(const g4_bf16x8*)ap;
                *(g4_bf16x8*)&v[8] = *(const g4_bf16x8*)(ap + 8);
            } else {
                #pragma unroll
                for (int j = 0; j < 16; j++) {
                    int gk = k0 + kc + j;
                    float f = (gm < M && gk < K) ? g4_ld(A, (size_t)gm * K + gk, af) : 0.f;
                    v[j] = (short)g4_f2bf(f);
                }
            }
            short* dst = &As[row * LDK + kc];
            *(g4_bf16x8*)dst       = *(g4_bf16x8*)&v[0];
            *(g4_bf16x8*)(dst + 8) = *(g4_bf16x8*)&v[8];
        }
        // ---- stage B tile transposed: Bs[n][k], n=tid&127, kc=(tid>>7)*16
        {
            int n  = tid & 127;
            int kc = (tid >> 7) * 16;
            int gn = bn + n;
            short v[16];
            #pragma unroll
            for (int j = 0; j < 16; j++) {
                int gk = k0 + kc + j;
                float f = (gk < K && gn < Nc) ? g4_ld(B, (size_t)gk * Nc + gn, isf) : 0.f;
                v[j] = (short)g4_f2bf(f);
            }
            short* dst = &Bs[n * LDK + kc];
            *(g4_bf16x8*)dst       = *(g4_bf16x8*)&v[0];
            *(g4_bf16x8*)(dst + 8) = *(g4_bf16x8*)&v[8];
        }
        __syncthreads();
        // ---- fragments + 16 MFMA
        g4_bf16x8 afr[4], bfr[4];
        #pragma unroll
        for (int it = 0; it < 4; it++) {
            int m = wr * 64 + it * 16 + l15;
            afr[it] = *(const g4_bf16x8*)&As[m * LDK + quad * 8];
        }
        #pragma unroll
        for (int jt = 0; jt < 4; jt++) {
            int n = wc * 64 + jt * 16 + l15;
            bfr[jt] = *(const g4_bf16x8*)&Bs[n * LDK + quad * 8];
        }
        #pragma unroll
        for (int it = 0; it < 4; it++)
            #pragma unroll
            for (int jt = 0; jt < 4; jt++)
                acc[it][jt] = __builtin_amdgcn_mfma_f32_16x16x32_bf16(
                    afr[it], bfr[jt], acc[it][jt], 0, 0, 0);
        __syncthreads();
    }
    // ---- store: D col = lane&15, row = quad*4 + r
    #pragma unroll
    for (int it = 0; it < 4; it++) {
        #pragma unroll
        for (int jt = 0; jt < 4; jt++) {
            int gn   = bn + wc * 64 + jt * 16 + l15;
            int row0 = bm + wr * 64 + it * 16 + quad * 4;
            if (gn >= Nc) continue;
            #pragma unroll
            for (int r = 0; r < 4; r++) {
                int gm = row0 + r;
                if (gm < M) C[(size_t)gm * Nc + gn] = g4_f2bf(acc[it][jt][r]);
            }
        }
    }
}

// ---------------------------------------------------------------------------
// Per-node attention logits. One wave per node; lane = channel.
// ---------------------------------------------------------------------------
__global__ __launch_bounds__(256) void g4_logits(
    const unsigned short* __restrict__ h, const void* __restrict__ att_src,
    const void* __restrict__ att_dst, const int* __restrict__ flags,
    float* __restrict__ a_src, float* __restrict__ a_dst) {
    int wid  = (blockIdx.x * blockDim.x + threadIdx.x) >> 6;
    int lane = threadIdx.x & 63;
    if (wid >= NN) return;
    const int isf = flags[0];
    const unsigned short* hp = h + (size_t)wid * HC;
    float s[4], d[4];
    #pragma unroll
    for (int hh = 0; hh < 4; hh++) {
        float v = g4_bf2f(hp[hh * 64 + lane]);
        s[hh] = v * g4_ld(att_src, hh * 64 + lane, isf);
        d[hh] = v * g4_ld(att_dst, hh * 64 + lane, isf);
    }
    for (int off = 32; off > 0; off >>= 1) {
        #pragma unroll
        for (int hh = 0; hh < 4; hh++) {
            s[hh] += __shfl_down(s[hh], off);
            d[hh] += __shfl_down(d[hh], off);
        }
    }
    if (lane == 0) {
        #pragma unroll
        for (int hh = 0; hh < 4; hh++) {
            a_src[wid * 4 + hh] = s[hh];
            a_dst[wid * 4 + hh] = d[hh];
        }
    }
}

// ---------------------------------------------------------------------------
// Wave-per-dst segment softmax + aggregation + bias + ELU -> bf16 out.
// ---------------------------------------------------------------------------
__global__ __launch_bounds__(256) void g4_aggregate(
    const unsigned short* __restrict__ h, const float* __restrict__ a_src,
    const float* __restrict__ a_dst, const int* __restrict__ rowptr,
    const int* __restrict__ col, const void* __restrict__ bias,
    const int* __restrict__ flags, unsigned short* __restrict__ xout) {
    int d    = (blockIdx.x * blockDim.x + threadIdx.x) >> 6;
    int lane = threadIdx.x & 63;
    if (d >= NN) return;
    const int isf = flags[0];
    const int start = rowptr[d], end = rowptr[d + 1];
    float ad[4];
    #pragma unroll
    for (int hh = 0; hh < 4; hh++) ad[hh] = a_dst[d * 4 + hh];

    // Pass A: max of leaky-relu logits
    float mx[4] = {-1e30f, -1e30f, -1e30f, -1e30f};
    for (int i = start + lane; i < end; i += 64) {
        int s = col[i];
        #pragma unroll
        for (int hh = 0; hh < 4; hh++) {
            float e = a_src[s * 4 + hh] + ad[hh];
            e = (e > 0.f) ? e : NEG_SLOPE * e;
            mx[hh] = fmaxf(mx[hh], e);
        }
    }
    for (int off = 32; off > 0; off >>= 1)
        #pragma unroll
        for (int hh = 0; hh < 4; hh++) mx[hh] = fmaxf(mx[hh], __shfl_xor(mx[hh], off));

    // Pass B: sum of exp
    float sm[4] = {0.f, 0.f, 0.f, 0.f};
    for (int i = start + lane; i < end; i += 64) {
        int s = col[i];
        #pragma unroll
        for (int hh = 0; hh < 4; hh++) {
            float e = a_src[s * 4 + hh] + ad[hh];
            e = (e > 0.f) ? e : NEG_SLOPE * e;
            sm[hh] += expf(e - mx[hh]);
        }
    }
    for (int off = 32; off > 0; off >>= 1)
        #pragma unroll
        for (int hh = 0; hh < 4; hh++) sm[hh] += __shfl_xor(sm[hh], off);
    float inv[4];
    #pragma unroll
    for (int hh = 0; hh < 4; hh++) inv[hh] = 1.f / sm[hh];

    // Pass C: weighted gather; lane = channel, alpha/src broadcast via shfl.
    float acc[4] = {0.f, 0.f, 0.f, 0.f};
    for (int base = start; base < end; base += 64) {
        int m = end - base;
        if (m > 64) m = 64;
        int   s_l   = 0;
        float al[4] = {0.f, 0.f, 0.f, 0.f};
        if (lane < m) {
            s_l = col[base + lane];
            #pragma unroll
            for (int hh = 0; hh < 4; hh++) {
                float e = a_src[s_l * 4 + hh] + ad[hh];
                e = (e > 0.f) ? e : NEG_SLOPE * e;
                al[hh] = expf(e - mx[hh]) * inv[hh];
            }
        }
        for (int j = 0; j < m; j++) {
            int s = __shfl(s_l, j);
            const unsigned short* hp = h + (size_t)s * HC;
            #pragma unroll
            for (int hh = 0; hh < 4; hh++)
                acc[hh] += __shfl(al[hh], j) * g4_bf2f(hp[hh * 64 + lane]);
        }
    }
    // Epilogue: +bias, ELU, bf16 store
    #pragma unroll
    for (int hh = 0; hh < 4; hh++) {
        float v = acc[hh] + g4_ld(bias, hh * 64 + lane, isf);
        v = (v > 0.f) ? v : (expf(v) - 1.f);
        xout[(size_t)d * HC + hh * 64 + lane] = g4_f2bf(v);
    }
}

// ---------------------------------------------------------------------------
// Fused MLP head, GEMM-tiled: 64 nodes/block, K=256 through LDS, 4x4 micro-
// tile over the 64 hidden cols, fused relu + b1 + dot(w2) + b2 epilogue.
// ---------------------------------------------------------------------------
__global__ __launch_bounds__(256) void g4_head2(
    const unsigned short* __restrict__ x, const void* __restrict__ w1,
    const void* __restrict__ b1, const void* __restrict__ w2,
    const void* __restrict__ b2, const int* __restrict__ flags,
    void* __restrict__ outp) {
    __shared__ float As[64][17];
    __shared__ float Bs[16][64];
    __shared__ float red[64][17];
    const int isf = flags[0];
    const int tid = threadIdx.x;
    const int bm  = blockIdx.x * 64;
    const int tx  = tid & 15;
    const int ty  = tid >> 4;
    float acc[4][4] = {};
    for (int k0 = 0; k0 < HC; k0 += 16) {
        for (int i = tid; i < 64 * 16; i += 256) {
            int m = i >> 4, kk = i & 15;
            int gm = bm + m;
            float v = 0.f;
            if (gm < NN) v = g4_bf2f(x[(size_t)gm * HC + k0 + kk]);
            As[m][kk] = v;
        }
        for (int i = tid; i < 16 * 64; i += 256) {
            int kk = i >> 6, n = i & 63;
            Bs[kk][n] = g4_ld(w1, (size_t)(k0 + kk) * 64 + n, isf);
        }
        __syncthreads();
        #pragma unroll
        for (int kk = 0; kk < 16; ++kk) {
            float a[4], b[4];
            #pragma unroll
            for (int i = 0; i < 4; i++) a[i] = As[ty * 4 + i][kk];
            #pragma unroll
            for (int j = 0; j < 4; j++) b[j] = Bs[kk][tx * 4 + j];
            #pragma unroll
            for (int i = 0; i < 4; i++)
                #pragma unroll
                for (int j = 0; j < 4; j++) acc[i][j] += a[i] * b[j];
        }
        __syncthreads();
    }
    float b1v[4], w2v[4];
    #pragma unroll
    for (int j = 0; j < 4; j++) {
        b1v[j] = g4_ld(b1, tx * 4 + j, isf);
        w2v[j] = g4_ld(w2, tx * 4 + j, isf);
    }
    #pragma unroll
    for (int i = 0; i < 4; i++) {
        float s = 0.f;
        #pragma unroll
        for (int j = 0; j < 4; j++) {
            float v = acc[i][j] + b1v[j];
            v = fmaxf(v, 0.f);
            s += v * w2v[j];
        }
        red[ty * 4 + i][tx] = s;
    }
    __syncthreads();
    if (tid < 64) {
        float s = 0.f;
        #pragma unroll
        for (int g = 0; g < 16; g++) s += red[tid][g];
        int gm = bm + tid;
        if (gm < NN) {
            float r = s + g4_ld(b2, 0, isf);
            if (isf) ((float*)outp)[gm] = r;
            else     ((unsigned short*)outp)[gm] = g4_f2bf(r);
        }
    }
}

// ---------------------------------------------------------------------------
extern "C" __attribute__((visibility("default")))
void kernel_launch(void* const* d_in, const int* in_sizes, int n_in,
                   void* d_out, int out_size, void* d_ws, size_t ws_size,
                   hipStream_t stream) {
    const void* x_in = d_in[0];
    const int*  ei   = (const int*)d_in[1];
    const void* W[3]    = {d_in[2], d_in[6], d_in[10]};
    const void* ASRC[3] = {d_in[3], d_in[7], d_in[11]};
    const void* ADST[3] = {d_in[4], d_in[8], d_in[12]};
    const void* BIAS[3] = {d_in[5], d_in[9], d_in[13]};
    const void* hw1 = d_in[14];
    const void* hb1 = d_in[15];
    const void* hw2 = d_in[16];
    const void* hb2 = d_in[17];

    char* base = (char*)d_ws;
    size_t woff = 0;
#define G4_TAKE(name, type, count) \
    type* name = (type*)(base + woff); \
    woff += (((size_t)(count)) * sizeof(type) + 255) & ~(size_t)255;
    G4_TAKE(flags,   int, 8)
    G4_TAKE(deg,     int, NN)
    G4_TAKE(cnt,     int, NN)
    G4_TAKE(tmp,     int, NN)
    G4_TAKE(partial, int, 256)
    G4_TAKE(rowptr,  int, NN + 1)
    G4_TAKE(col,     int, ETOT)
    G4_TAKE(asr,     float, (size_t)NN * 4)
    G4_TAKE(adsb,    float, (size_t)NN * 4)
    G4_TAKE(hbuf,    unsigned short, (size_t)NN * HC)
    G4_TAKE(xbuf,    unsigned short, (size_t)NN * HC)
#undef G4_TAKE

    const int SCAN_BLOCKS = (NN + 255) / 256;          // 196
    const int EDGE_BLOCKS = (ETOT + 255) / 256;        // 3321
    const int WAVE_BLOCKS = (NN + 3) / 4;              // 12500 (4 waves/block)
    const int TILE_BLOCKS = (NN + 63) / 64;            // 782

    g4_detect<<<1, 256, 0, stream>>>((const unsigned int*)x_in, ei, flags);
    g4_zero<<<SCAN_BLOCKS, 256, 0, stream>>>(deg, cnt, (unsigned int*)d_out);

    g4_hist<<<EDGE_BLOCKS, 256, 0, stream>>>(ei, flags, deg);
    g4_scan_block<<<SCAN_BLOCKS, 256, 0, stream>>>(deg, tmp, partial);
    g4_scan_partial<<<1, 256, 0, stream>>>(partial, SCAN_BLOCKS, rowptr + NN);
    g4_scan_add<<<SCAN_BLOCKS, 256, 0, stream>>>(tmp, partial, rowptr);
    g4_fill_csr<<<EDGE_BLOCKS, 256, 0, stream>>>(ei, flags, rowptr, cnt, col);

    // 3 GAT layers (MFMA GEMM: 128x128 tiles)
    dim3 mgrid((NN + 127) / 128, HC / 128);            // 391 x 2
    for (int l = 0; l < 3; l++) {
        if (l == 0) {
            g4_gemm_mfma<<<mgrid, 256, 0, stream>>>(x_in, 0, W[l], flags, hbuf, NN, 61, HC);
        } else {
            g4_gemm_mfma<<<mgrid, 256, 0, stream>>>(xbuf, 1, W[l], flags, hbuf, NN, HC, HC);
        }
        g4_logits<<<WAVE_BLOCKS, 256, 0, stream>>>(hbuf, ASRC[l], ADST[l], flags, asr, adsb);
        g4_aggregate<<<WAVE_BLOCKS, 256, 0, stream>>>(hbuf, asr, adsb, rowptr, col,
                                                      BIAS[l], flags, xbuf);
    }
    g4_head2<<<TILE_BLOCKS, 256, 0, stream>>>(xbuf, hw1, hb1, hw2, hb2, flags, d_out);
}